// Round 7
// baseline (1677.703 us; speedup 1.0000x reference)
//
#include <hip/hip_runtime.h>
#include <cstdint>
#include <cstddef>

#define BSZ    32
#define SEQL   2048
#define ENCD   512
#define DE     1024   // DEC + ENC
#define NHEADS 8
#define IHD    1024   // INTERM * HEADS

typedef unsigned short u16;
typedef __bf16 bf16x8 __attribute__((ext_vector_type(8)));
typedef float floatx4 __attribute__((ext_vector_type(4)));
typedef unsigned short u16x8 __attribute__((ext_vector_type(8)));

__device__ __forceinline__ u16 f2bf(float f) {
    unsigned int u = __float_as_uint(f);
    u = (u + 0x7FFFu + ((u >> 16) & 1u)) >> 16;   // RNE
    return (u16)u;
}
__device__ __forceinline__ float softplus_f(float x) {
    return fmaxf(x, 0.0f) + log1pf(__expf(-fabsf(x)));
}
__device__ __forceinline__ float tanh_fast(float x) {
    const float e = __expf(2.0f * x);
    return 1.0f - 2.0f / (e + 1.0f);
}
__device__ __forceinline__ void async_cp16(u16* lds, const u16* g) {
    __builtin_amdgcn_global_load_lds(
        (const __attribute__((address_space(1))) unsigned int*)g,
        (__attribute__((address_space(3))) unsigned int*)lds, 16, 0, 0);
}

// ---------------------------------------------------------------------------
// enc (fp32, [64536 rows][512]) -> enc_p (bf16 fragment-chunk layout):
// enc_p[mb][kc 0..63][m 0..63] 16B-chunk = bf16(enc[mb*64+m][kc*8 .. +8])
// One block per 64-row m-block; LDS transpose keeps both sides coalesced.
// ---------------------------------------------------------------------------
__global__ __launch_bounds__(256) void conv_encp_kernel(const float* __restrict__ enc,
                                                        u16* __restrict__ encp) {
    __shared__ float tile[64][132];
    const int mb = blockIdx.x, tid = threadIdx.x;
    for (int kq = 0; kq < 4; ++kq) {
        __syncthreads();
        for (int i = tid; i < 8192; i += 256) {
            const int m = i >> 7, kk = i & 127;
            tile[m][kk] = enc[((size_t)mb * 64 + m) * 512 + kq * 128 + kk];
        }
        __syncthreads();
        for (int j = tid; j < 1024; j += 256) {
            const int m = j & 63, kcl = j >> 6;      // kcl 0..15
            const float* tp = &tile[m][kcl * 8];
            u16x8 o;
            #pragma unroll
            for (int t = 0; t < 8; ++t) o[t] = f2bf(tp[t]);
            *(u16x8*)&encp[((size_t)mb * 4096 + (kq * 16 + kcl) * 64 + m) * 8] = o;
        }
    }
}

// ---------------------------------------------------------------------------
// bid<128: Wv (fp32 [512 k][1024 n]) -> wvTp (bf16, staged-chunk layout):
//   wvTp[c = ks*2+nh][q 0..3][nloc 0..511] 16B-chunk
//     = bf16(Wv[ks*32 + q*8 .. +8][nh*512 + nloc])
// bid==128: Wf -> bf16 (8192 + 8 pad)
// ---------------------------------------------------------------------------
__global__ __launch_bounds__(256) void conv_w_kernel(const float* __restrict__ Wv,
                                                     const float* __restrict__ Wf,
                                                     u16* __restrict__ wvTp,
                                                     u16* __restrict__ wfb) {
    __shared__ float tile[64][65];   // [kk][nn]
    const int bid = blockIdx.x, tid = threadIdx.x;
    if (bid == 128) {
        for (int i = tid; i < 8200; i += 256)
            wfb[i] = (i < 8192) ? f2bf(Wf[i]) : (u16)0;
        return;
    }
    const int nt64 = bid & 15, kt64 = bid >> 4;
    for (int i = tid; i < 4096; i += 256) {
        const int kk = i >> 6, nn = i & 63;
        tile[kk][nn] = Wv[(size_t)(kt64 * 64 + kk) * IHD + nt64 * 64 + nn];
    }
    __syncthreads();
    for (int j = tid; j < 512; j += 256) {          // (kcl 0..7) x (nn 0..63)
        const int nn = j & 63, kcl = j >> 6;
        const int ks = kt64 * 2 + (kcl >> 2);
        const int q  = kcl & 3;
        const int n  = nt64 * 64 + nn;
        const int nh = n >> 9, nloc = n & 511;
        const int c  = ks * 2 + nh;
        u16x8 o;
        #pragma unroll
        for (int t = 0; t < 8; ++t) o[t] = f2bf(tile[kcl * 8 + t][nn]);
        *(u16x8*)&wvTp[((size_t)(c * 4 + q) * 512 + nloc) * 8] = o;
    }
}

// ---------------------------------------------------------------------------
// prep: query = dec@Wq+bq ; beta = sp(dec@Wb+bb) ; kappa += sp(dec@Wk+bk)
// ---------------------------------------------------------------------------
__global__ __launch_bounds__(256) void prep_kernel(
    const float* __restrict__ dec, const float* __restrict__ kappa_in,
    const float* __restrict__ Wq, const float* __restrict__ bq,
    const float* __restrict__ Wb, const float* __restrict__ bb,
    const float* __restrict__ Wk, const float* __restrict__ bk,
    float* __restrict__ query_ws, float* __restrict__ beta_ws,
    float* __restrict__ kappa_out)
{
    __shared__ float s_dec[DE];
    __shared__ float s_red[256];
    const int b = blockIdx.x, y = blockIdx.y, tid = threadIdx.x;
    for (int i = tid; i < DE; i += 256) s_dec[i] = dec[b * DE + i];
    __syncthreads();

    if (y < 32) {
        const int cl = tid & 31, kg = tid >> 5;
        const int col = y * 32 + cl;
        float a = 0.f;
        const float* w = Wq + col;
        #pragma unroll 4
        for (int k = kg * 128; k < kg * 128 + 128; ++k)
            a = fmaf(s_dec[k], w[(size_t)k * IHD], a);
        s_red[tid] = a;
        __syncthreads();
        if (tid < 32) {
            float s = 0.f;
            #pragma unroll
            for (int i = 0; i < 8; ++i) s += s_red[i * 32 + tid];
            query_ws[(size_t)b * IHD + col] = s + bq[col];
        }
    } else {
        const int h = tid & 7, kg = tid >> 3;
        float ab = 0.f, ak = 0.f;
        for (int k = kg * 32; k < kg * 32 + 32; ++k) {
            const float d = s_dec[k];
            ab = fmaf(d, Wb[k * NHEADS + h], ab);
            ak = fmaf(d, Wk[k * NHEADS + h], ak);
        }
        s_red[tid] = ab;
        __syncthreads();
        for (int off = 128; off >= 8; off >>= 1) {
            if (tid < off) s_red[tid] += s_red[tid + off];
            __syncthreads();
        }
        const float abT = (tid < 8) ? s_red[tid] : 0.f;
        __syncthreads();
        s_red[tid] = ak;
        __syncthreads();
        for (int off = 128; off >= 8; off >>= 1) {
            if (tid < off) s_red[tid] += s_red[tid + off];
            __syncthreads();
        }
        if (tid < 8) {
            beta_ws[b * NHEADS + tid]   = softplus_f(bb[tid] + abT);
            kappa_out[b * NHEADS + tid] = kappa_in[b * NHEADS + tid]
                                        + softplus_f(bk[tid] + s_red[tid]);
        }
    }
}

// ---------------------------------------------------------------------------
// Main fused GEMM. 1024 blocks x 512 thr (8 waves), LDS 128 KB.
// A-tile (64 rows x K512, bf16) staged ONCE from enc_p via streaming
// global_load_lds. Full-N accumulation: acc[4 m-tiles][8 col-slices] (128
// VGPR). K-loop: 32 chunks (16 ks x 2 n-halves), B double-buffered 32 KB from
// wvTp (streaming glds, L2-resident). Fragment ds_reads are contiguous 256B
// per 16 lanes -> conflict-free, no swizzle.
// Wave layout: wave w owns cols (i*8+w)*16+fr for i 0..7; slice nn <-> i=nn.
// Epilogue per slice: tanh -> tT (reuses dead B buffers) -> stage-2 MFMA
// (t @ Wf, k-halves across wc) -> cross-wave reduce -> score.
// ---------------------------------------------------------------------------
__global__ __launch_bounds__(512, 2) void gemm_score_kernel(
    const u16* __restrict__ encp, const u16* __restrict__ wvTp,
    const float* __restrict__ bv, const u16* __restrict__ wfb,
    const float* __restrict__ bf_g, const float* __restrict__ mask,
    const float* __restrict__ query_ws, const float* __restrict__ beta_ws,
    const float* __restrict__ kappa_out, float* __restrict__ score_out)
{
    __shared__ __align__(16) unsigned char smem[131072];
    u16*    Ab  = (u16*)smem;                       // 65536 B, [kc 0..63][m 0..63] chunks
    u16*    Bb0 = (u16*)(smem + 65536);             // 32768 B
    u16*    Bb1 = (u16*)(smem + 98304);             // 32768 B
    __bf16* tT  = (__bf16*)(smem + 65536);          // 17408 B (epilogue; B dead)
    float*  s_p = (float*)(smem + 65536 + 17408);   //  4096 B

    const int tid  = threadIdx.x;
    const int mb   = blockIdx.x;
    const int m0   = mb * 64;
    const int b    = mb >> 5;                       // 32 blocks per batch
    const int lane = tid & 63;
    const int w    = tid >> 6;                      // 0..7
    const int fr   = lane & 15, quad = lane >> 4;

    // ---- prologue: stage A (64 KB) + B chunk 0 (32 KB), both streaming
    {
        const u16* srcA = encp + (size_t)mb * 32768;
        #pragma unroll
        for (int r = 0; r < 8; ++r)
            async_cp16(Ab + (size_t)(r * 512 + tid) * 8, srcA + (size_t)(r * 512 + tid) * 8);
        #pragma unroll
        for (int r = 0; r < 4; ++r)
            async_cp16(Bb0 + (size_t)(r * 512 + tid) * 8, wvTp + (size_t)(r * 512 + tid) * 8);
    }
    __syncthreads();

    floatx4 acc[4][8] = {};

    // ---- K-loop: 32 chunks (ks = c>>1, n-half = c&1), B double-buffered
    for (int c = 0; c < 32; ++c) {
        u16* curB = (c & 1) ? Bb1 : Bb0;
        if (c < 31) {
            u16* nxtB = (c & 1) ? Bb0 : Bb1;
            const u16* srcB = wvTp + (size_t)(c + 1) * 16384;
            #pragma unroll
            for (int r = 0; r < 4; ++r)
                async_cp16(nxtB + (size_t)(r * 512 + tid) * 8,
                           srcB + (size_t)(r * 512 + tid) * 8);
        }
        const int ks = c >> 1, nh = c & 1;

        bf16x8 bfrag[4];
        #pragma unroll
        for (int i = 0; i < 4; ++i) {
            const int nloc = (i * 8 + w) * 16 + fr;
            bfrag[i] = *(const bf16x8*)&curB[(size_t)(quad * 512 + nloc) * 8];
        }
        bf16x8 afrag[4];
        #pragma unroll
        for (int mt = 0; mt < 4; ++mt)
            afrag[mt] = *(const bf16x8*)&Ab[(size_t)((ks * 4 + quad) * 64 + mt * 16 + fr) * 8];

        #pragma unroll
        for (int mt = 0; mt < 4; ++mt)
            #pragma unroll
            for (int i = 0; i < 4; ++i)
                acc[mt][nh * 4 + i] = __builtin_amdgcn_mfma_f32_16x16x32_bf16(
                    afrag[mt], bfrag[i], acc[mt][nh * 4 + i], 0, 0, 0);
        __syncthreads();
    }

    // ---- epilogue: per 128-col slice nn: tanh -> tT -> stage-2 MFMA
    const int wr = w >> 1, wc = w & 1;
    floatx4 acc2 = {};
    for (int nn = 0; nn < 8; ++nn) {
        const int n0 = nn * 128;
        const int colg = n0 + w * 16 + fr;
        const float qv = query_ws[(size_t)b * IHD + colg] + bv[colg];
        #pragma unroll
        for (int mt = 0; mt < 4; ++mt)
            #pragma unroll
            for (int reg = 0; reg < 4; ++reg)
                tT[(mt * 16 + quad * 4 + reg) * 136 + (w * 16 + fr)] =
                    (__bf16)tanh_fast(acc[mt][nn][reg] + qv);
        __syncthreads();

        bf16x8 wfr[2];
        #pragma unroll
        for (int kk = 0; kk < 2; ++kk)
            #pragma unroll
            for (int j = 0; j < 8; ++j)
                wfr[kk][j] = *(const __bf16*)
                    &wfb[(n0 + (wc * 2 + kk) * 32 + quad * 8 + j) * 8 + fr];
        #pragma unroll
        for (int kk = 0; kk < 2; ++kk) {
            const bf16x8 ta = *(const bf16x8*)
                &tT[(wr * 16 + fr) * 136 + (wc * 2 + kk) * 32 + quad * 8];
            acc2 = __builtin_amdgcn_mfma_f32_16x16x32_bf16(ta, wfr[kk], acc2, 0, 0, 0);
        }
        __syncthreads();
    }

    // ---- cross-wave k-half reduce + score
    if (fr < NHEADS) {
        #pragma unroll
        for (int reg = 0; reg < 4; ++reg)
            s_p[((wr * 2 + wc) * 16 + quad * 4 + reg) * 8 + fr] = acc2[reg];
    }
    __syncthreads();

    if (tid < 512) {
        const int row = tid >> 3;                   // 0..63
        const int h   = tid & 7;
        const float p = s_p[(((row >> 4) * 2 + 0) * 16 + (row & 15)) * 8 + h]
                      + s_p[(((row >> 4) * 2 + 1) * 16 + (row & 15)) * 8 + h];
        const int grow = m0 + row;
        const int s = grow & 2047;
        const float alpha = softplus_f(p + bf_g[h]) * mask[grow];
        const float bet = beta_ws[b * NHEADS + h];
        const float kap = kappa_out[b * NHEADS + h];
        const float du  = kap - (float)s;
        score_out[(size_t)grow * NHEADS + h] = alpha * __expf(-bet * du * du);
    }
}

// ---------------------------------------------------------------------------
// context partials: part[sc][b][h][e] = sum_{s in chunk} score[b,s,h]*enc[b,s,e]
// grid (b=32, sc=16). Wave w owns heads {2w,2w+1} x all 512 e. fp32 enc.
// ---------------------------------------------------------------------------
__global__ __launch_bounds__(256) void context_kernel(
    const float* __restrict__ enc, const float* __restrict__ score,
    float* __restrict__ ctx_part)
{
    __shared__ float s_sc[128 * NHEADS];
    const int b = blockIdx.x, sc = blockIdx.y, tid = threadIdx.x;
    const int lane = tid & 63, w = tid >> 6;
    const int e8 = lane * 8;
    const size_t srow0 = (size_t)b * SEQL + sc * 128;

    for (int i = tid; i < 128 * NHEADS; i += 256)
        s_sc[i] = score[srow0 * NHEADS + i];
    __syncthreads();

    float acc0[8] = {}, acc1[8] = {};
    const float* ep = enc + srow0 * ENCD + e8;
    #pragma unroll 4
    for (int s = 0; s < 128; ++s) {
        const float4 e0 = *(const float4*)(ep + (size_t)s * ENCD);
        const float4 e1 = *(const float4*)(ep + (size_t)s * ENCD + 4);
        const float ef[8] = {e0.x, e0.y, e0.z, e0.w, e1.x, e1.y, e1.z, e1.w};
        const float2 sc2 = *(const float2*)&s_sc[s * NHEADS + 2 * w];
        #pragma unroll
        for (int j = 0; j < 8; ++j) {
            acc0[j] = fmaf(sc2.x, ef[j], acc0[j]);
            acc1[j] = fmaf(sc2.y, ef[j], acc1[j]);
        }
    }

    float* outp = ctx_part + ((size_t)sc * BSZ + b) * (NHEADS * ENCD);
    *(float4*)&outp[(2 * w + 0) * ENCD + e8]     = make_float4(acc0[0], acc0[1], acc0[2], acc0[3]);
    *(float4*)&outp[(2 * w + 0) * ENCD + e8 + 4] = make_float4(acc0[4], acc0[5], acc0[6], acc0[7]);
    *(float4*)&outp[(2 * w + 1) * ENCD + e8]     = make_float4(acc1[0], acc1[1], acc1[2], acc1[3]);
    *(float4*)&outp[(2 * w + 1) * ENCD + e8 + 4] = make_float4(acc1[4], acc1[5], acc1[6], acc1[7]);
}

// ---------------------------------------------------------------------------
// ctx_ws[i] = sum_sc part[sc][i]   (i < 131072)
// ---------------------------------------------------------------------------
__global__ __launch_bounds__(256) void ctx_reduce_kernel(
    const float* __restrict__ part, float* __restrict__ ctx_ws)
{
    const int i = blockIdx.x * 256 + threadIdx.x;
    float a = 0.f;
    #pragma unroll
    for (int sc = 0; sc < 16; ++sc)
        a += part[(size_t)sc * 131072 + i];
    ctx_ws[i] = a;
}

// ---------------------------------------------------------------------------
// out_ctx[b,j] = ctx[b,:] @ Wfc[:,j] + bfc[j]
// ---------------------------------------------------------------------------
__global__ __launch_bounds__(256) void final_kernel(
    const float* __restrict__ ctx_ws, const float* __restrict__ Wfc,
    const float* __restrict__ bfc, float* __restrict__ out_ctx)
{
    __shared__ float s_ctx[32][128];
    const int jc = blockIdx.x, ks = blockIdx.y, tid = threadIdx.x;
    const int jl = tid & 31, bg = tid >> 5;
    const int j = jc * 32 + jl;
    float a0 = 0.f, a1 = 0.f, a2 = 0.f, a3 = 0.f;

    for (int t = 0; t < 4; ++t) {
        const int k0 = ks * 512 + t * 128;
        __syncthreads();
        for (int i = tid; i < 32 * 128; i += 256) {
            const int bb2 = i >> 7, kk = i & 127;
            s_ctx[bb2][kk] = ctx_ws[(size_t)bb2 * (NHEADS * ENCD) + k0 + kk];
        }
        __syncthreads();
        for (int kk = 0; kk < 128; ++kk) {
            const float wv = Wfc[(size_t)(k0 + kk) * ENCD + j];
            a0 = fmaf(s_ctx[bg * 4 + 0][kk], wv, a0);
            a1 = fmaf(s_ctx[bg * 4 + 1][kk], wv, a1);
            a2 = fmaf(s_ctx[bg * 4 + 2][kk], wv, a2);
            a3 = fmaf(s_ctx[bg * 4 + 3][kk], wv, a3);
        }
    }
    const float bias = (ks == 0) ? bfc[j] : 0.0f;
    atomicAdd(&out_ctx[(bg * 4 + 0) * ENCD + j], a0 + bias);
    atomicAdd(&out_ctx[(bg * 4 + 1) * ENCD + j], a1 + bias);
    atomicAdd(&out_ctx[(bg * 4 + 2) * ENCD + j], a2 + bias);
    atomicAdd(&out_ctx[(bg * 4 + 3) * ENCD + j], a3 + bias);
}

// ---------------------------------------------------------------------------
extern "C" void kernel_launch(void* const* d_in, const int* in_sizes, int n_in,
                              void* d_out, int out_size, void* d_ws, size_t ws_size,
                              hipStream_t stream)
{
    const float* enc   = (const float*)d_in[0];
    const float* dec   = (const float*)d_in[1];
    const float* kapin = (const float*)d_in[2];
    const float* mask  = (const float*)d_in[3];
    const float* Wv    = (const float*)d_in[4];
    const float* bv    = (const float*)d_in[5];
    const float* Wq    = (const float*)d_in[6];
    const float* bq    = (const float*)d_in[7];
    const float* Wf    = (const float*)d_in[8];
    const float* bf    = (const float*)d_in[9];
    const float* Wb    = (const float*)d_in[10];
    const float* bb    = (const float*)d_in[11];
    const float* Wk    = (const float*)d_in[12];
    const float* bk    = (const float*)d_in[13];
    const float* Wfc   = (const float*)d_in[14];
    const float* bfc   = (const float*)d_in[15];

    // outputs: context(32*512) | kappa(32*8) | score(32*2048*8)
    float* out       = (float*)d_out;
    float* out_ctx   = out;
    float* out_kappa = out + 16384;
    float* out_score = out + 16640;

    // workspace layout (bytes)
    char* w = (char*)d_ws;
    u16*   encp     = (u16*)w;                     // 67108864 B
    u16*   wvTp     = (u16*)(w + 67108864);        //  1048576 B
    u16*   wfb      = (u16*)(w + 68157440);        //    16400 B
    float* q_ws     = (float*)(w + 68173840);      //   131072 B
    float* beta_ws  = (float*)(w + 68304912);      //     1024 B
    float* ctx_ws   = (float*)(w + 68305936);      //   524288 B
    float* ctx_part = (float*)(w + 68830224);      //  8388608 B
                                                   // total 77218832 B

    hipMemsetAsync(out_ctx, 0, 16384 * sizeof(float), stream);

    conv_encp_kernel<<<dim3(1024), dim3(256), 0, stream>>>(enc, encp);
    conv_w_kernel<<<dim3(129), dim3(256), 0, stream>>>(Wv, Wf, wvTp, wfb);

    prep_kernel<<<dim3(BSZ, 33), dim3(256), 0, stream>>>(
        dec, kapin, Wq, bq, Wb, bb, Wk, bk, q_ws, beta_ws, out_kappa);

    gemm_score_kernel<<<dim3(1024), dim3(512), 0, stream>>>(
        encp, wvTp, bv, wfb, bf, mask, q_ws, beta_ws, out_kappa, out_score);

    context_kernel<<<dim3(BSZ, 16), dim3(256), 0, stream>>>(
        enc, out_score, ctx_part);

    ctx_reduce_kernel<<<dim3(512), dim3(256), 0, stream>>>(ctx_part, ctx_ws);

    final_kernel<<<dim3(16, 8), dim3(256), 0, stream>>>(
        ctx_ws, Wfc, bfc, out_ctx);
}